// Round 7
// baseline (172.944 us; speedup 1.0000x reference)
//
#include <hip/hip_runtime.h>
#include <math.h>

// WL1 loss over [B=16, C=3, H=512, W=512] fp32.
//   r = sum_c|hr-sr|/255 ; e = sum_c|hr-ema|/255
//   patch_w[b] = (unbiased var of r over sample)^0.2
//   pixel_w = unbiased 3x3 local var of r (reflect pad)
//   loss = mean(|w*sr - w*hr|) = (1/N) sum patch_w * pixel_w * mask * 255*r
//
// R7: pass1 rebuilt for memory-level parallelism. R6 compiled to 24 VGPRs ->
// 9 loads serialized into ~3 latency-bound batches (block lifetime ~3.4us,
// 16 blocks/CU -> 54us). Now: 2 groups/thread (two coalesced half-sweeps),
// all 18 float4 loads live before any use, launch_bounds(256,4) (<=128 VGPR).
// Pass 2: 3x3 stencil over compact rf (sign bit = mask). Pass 3: fold.

#define BB 16
#define HH 512
#define WW 512
#define HW (HH * WW)
#define CHW (3 * HW)
#define GRP_PER_B (HW / 4)          // 65536 float4 groups per image
#define NGRP (BB * GRP_PER_B)       // 1,048,576
#define HALF (NGRP / 2)             // 524,288 (images 0..7 | 8..15)
#define P1_BLOCKS 2048              // 256 threads x 2 groups each
#define P1_PER_B 256                // partials per batch (layout [256b,256b+256))
#define STRIPS 128                  // 512 rows / 4
#define P2_BLOCKS (BB * STRIPS)     // 2048
#define P2_PER_B STRIPS

__device__ __forceinline__ int reflect_h(int gh) {
  gh = gh < 0 ? -gh : gh;
  return gh >= HH ? 2 * HH - 2 - gh : gh;
}

// ---------------- Pass 1: streaming residual + mask + patch sums ----------
// Thread t: group gA = bid*256+tid (image bA=gA>>16 in 0..7) and
//           gB = gA + HALF (image bA+8, same pixel offset).
// All 18 float4 loads issued before any consumption (MLP).
__global__ __launch_bounds__(256, 4) void wl1_pass1(
    const float* __restrict__ sr, const float* __restrict__ srema,
    const float* __restrict__ hr, float4* __restrict__ rfbuf,
    float* __restrict__ p_sum, float* __restrict__ p_sum2) {
  const int tid = threadIdx.x;
  const int gA = blockIdx.x * 256 + tid;
  const size_t offA = (size_t)4 * gA;          // element offset in image-major layout
  const size_t offB = offA + (size_t)4 * HALF;

  const float* spA = sr + ((offA >> 18) * CHW + (offA & 262143));
  // NOTE: offA>>18 == image index (262144 px/image); offA&262143 == pixel offset
  const float* hpA = hr + ((offA >> 18) * CHW + (offA & 262143));
  const float* mpA = srema + ((offA >> 18) * CHW + (offA & 262143));
  const float* spB = sr + ((offB >> 18) * CHW + (offB & 262143));
  const float* hpB = hr + ((offB >> 18) * CHW + (offB & 262143));
  const float* mpB = srema + ((offB >> 18) * CHW + (offB & 262143));

  // ---- issue all 18 loads ----
  float4 sA0 = *(const float4*)spA;
  float4 sA1 = *(const float4*)(spA + HW);
  float4 sA2 = *(const float4*)(spA + 2 * HW);
  float4 hA0 = *(const float4*)hpA;
  float4 hA1 = *(const float4*)(hpA + HW);
  float4 hA2 = *(const float4*)(hpA + 2 * HW);
  float4 mA0 = *(const float4*)mpA;
  float4 mA1 = *(const float4*)(mpA + HW);
  float4 mA2 = *(const float4*)(mpA + 2 * HW);
  float4 sB0 = *(const float4*)spB;
  float4 sB1 = *(const float4*)(spB + HW);
  float4 sB2 = *(const float4*)(spB + 2 * HW);
  float4 hB0 = *(const float4*)hpB;
  float4 hB1 = *(const float4*)(hpB + HW);
  float4 hB2 = *(const float4*)(hpB + 2 * HW);
  float4 mB0 = *(const float4*)mpB;
  float4 mB1 = *(const float4*)(mpB + HW);
  float4 mB2 = *(const float4*)(mpB + 2 * HW);

  // ---- consume A ----
  float4 rA, eA, oA;
  rA.x = (fabsf(hA0.x - sA0.x) + fabsf(hA1.x - sA1.x) + fabsf(hA2.x - sA2.x)) / 255.0f;
  rA.y = (fabsf(hA0.y - sA0.y) + fabsf(hA1.y - sA1.y) + fabsf(hA2.y - sA2.y)) / 255.0f;
  rA.z = (fabsf(hA0.z - sA0.z) + fabsf(hA1.z - sA1.z) + fabsf(hA2.z - sA2.z)) / 255.0f;
  rA.w = (fabsf(hA0.w - sA0.w) + fabsf(hA1.w - sA1.w) + fabsf(hA2.w - sA2.w)) / 255.0f;
  eA.x = (fabsf(hA0.x - mA0.x) + fabsf(hA1.x - mA1.x) + fabsf(hA2.x - mA2.x)) / 255.0f;
  eA.y = (fabsf(hA0.y - mA0.y) + fabsf(hA1.y - mA1.y) + fabsf(hA2.y - mA2.y)) / 255.0f;
  eA.z = (fabsf(hA0.z - mA0.z) + fabsf(hA1.z - mA1.z) + fabsf(hA2.z - mA2.z)) / 255.0f;
  eA.w = (fabsf(hA0.w - mA0.w) + fabsf(hA1.w - mA1.w) + fabsf(hA2.w - mA2.w)) / 255.0f;
  oA.x = (rA.x < eA.x) ? -rA.x : rA.x;
  oA.y = (rA.y < eA.y) ? -rA.y : rA.y;
  oA.z = (rA.z < eA.z) ? -rA.z : rA.z;
  oA.w = (rA.w < eA.w) ? -rA.w : rA.w;
  rfbuf[gA] = oA;

  // ---- consume B ----
  float4 rB, eB, oB;
  rB.x = (fabsf(hB0.x - sB0.x) + fabsf(hB1.x - sB1.x) + fabsf(hB2.x - sB2.x)) / 255.0f;
  rB.y = (fabsf(hB0.y - sB0.y) + fabsf(hB1.y - sB1.y) + fabsf(hB2.y - sB2.y)) / 255.0f;
  rB.z = (fabsf(hB0.z - sB0.z) + fabsf(hB1.z - sB1.z) + fabsf(hB2.z - sB2.z)) / 255.0f;
  rB.w = (fabsf(hB0.w - sB0.w) + fabsf(hB1.w - sB1.w) + fabsf(hB2.w - sB2.w)) / 255.0f;
  eB.x = (fabsf(hB0.x - mB0.x) + fabsf(hB1.x - mB1.x) + fabsf(hB2.x - mB2.x)) / 255.0f;
  eB.y = (fabsf(hB0.y - mB0.y) + fabsf(hB1.y - mB1.y) + fabsf(hB2.y - mB2.y)) / 255.0f;
  eB.z = (fabsf(hB0.z - mB0.z) + fabsf(hB1.z - mB1.z) + fabsf(hB2.z - mB2.z)) / 255.0f;
  eB.w = (fabsf(hB0.w - mB0.w) + fabsf(hB1.w - mB1.w) + fabsf(hB2.w - mB2.w)) / 255.0f;
  oB.x = (rB.x < eB.x) ? -rB.x : rB.x;
  oB.y = (rB.y < eB.y) ? -rB.y : rB.y;
  oB.z = (rB.z < eB.z) ? -rB.z : rB.z;
  oB.w = (rB.w < eB.w) ? -rB.w : rB.w;
  rfbuf[gA + HALF] = oB;

  // ---- patch sums: A belongs to batch bA, B to batch bA+8 ----
  float v1A = rA.x + rA.y + rA.z + rA.w;
  float v2A = rA.x * rA.x + rA.y * rA.y + rA.z * rA.z + rA.w * rA.w;
  float v1B = rB.x + rB.y + rB.z + rB.w;
  float v2B = rB.x * rB.x + rB.y * rB.y + rB.z * rB.z + rB.w * rB.w;
#pragma unroll
  for (int off = 32; off > 0; off >>= 1) {
    v1A += __shfl_down(v1A, off, 64);
    v2A += __shfl_down(v2A, off, 64);
    v1B += __shfl_down(v1B, off, 64);
    v2B += __shfl_down(v2B, off, 64);
  }
  __shared__ float red[4][4];
  const int wave = tid >> 6, lane = tid & 63;
  if (lane == 0) {
    red[0][wave] = v1A;
    red[1][wave] = v2A;
    red[2][wave] = v1B;
    red[3][wave] = v2B;
  }
  __syncthreads();
  if (tid == 0) {
    // layout: A partials at [bid], B partials at [2048+bid];
    // batch b's 256 partials land contiguously at [256*b, 256*b+256) for all b.
    p_sum[blockIdx.x] = red[0][0] + red[0][1] + red[0][2] + red[0][3];
    p_sum2[blockIdx.x] = red[1][0] + red[1][1] + red[1][2] + red[1][3];
    p_sum[P1_BLOCKS + blockIdx.x] = red[2][0] + red[2][1] + red[2][2] + red[2][3];
    p_sum2[P1_BLOCKS + blockIdx.x] = red[3][0] + red[3][1] + red[3][2] + red[3][3];
  }
}

// ---------------- Pass 2: 3x3 stencil over compact rf --------------------
__global__ __launch_bounds__(256, 8) void wl1_pass2(
    const float4* __restrict__ rfbuf, float* __restrict__ p_loss) {
  __shared__ float rt[6][WW];  // |rf| for halo rows h0-1 .. h0+4
  __shared__ float ft[4][WW];  // premasked 255*r for center rows
  const int tid = threadIdx.x;
  const int bid = blockIdx.x;
  const int b = bid >> 7;
  const int h0 = (bid & 127) << 2;

#pragma unroll
  for (int it = 0; it < 3; ++it) {
    const int item = it * 256 + tid;
    const int row = item >> 7;  // 0..5 (wave-uniform)
    const int g = item & 127;
    const int gh = reflect_h(h0 - 1 + row);
    float4 v = rfbuf[(b << 16) + gh * 128 + g];
    float4 a4;
    a4.x = fabsf(v.x); a4.y = fabsf(v.y); a4.z = fabsf(v.z); a4.w = fabsf(v.w);
    *(float4*)&rt[row][4 * g] = a4;
    if (row >= 1 && row <= 4) {
      float4 f4;
      f4.x = (__float_as_uint(v.x) >> 31) ? 0.0f : 255.0f * a4.x;
      f4.y = (__float_as_uint(v.y) >> 31) ? 0.0f : 255.0f * a4.y;
      f4.z = (__float_as_uint(v.z) >> 31) ? 0.0f : 255.0f * a4.z;
      f4.w = (__float_as_uint(v.w) >> 31) ? 0.0f : 255.0f * a4.w;
      *(float4*)&ft[row - 1][4 * g] = f4;
    }
  }
  __syncthreads();

  const int g = tid & 127;
  const int r0 = tid >> 7;  // 0 or 1
  const int li = (g == 0) ? 1 : 4 * g - 1;
  const int ri = (g == 127) ? 510 : 4 * g + 4;
  float v3 = 0.f;
#pragma unroll
  for (int k = 0; k < 2; ++k) {
    const int orow = r0 + 2 * k;  // output row within strip (0..3)
    float cs[6] = {0, 0, 0, 0, 0, 0}, cq[6] = {0, 0, 0, 0, 0, 0};
#pragma unroll
    for (int dr = 0; dr < 3; ++dr) {
      const int row = orow + dr;
      float4 c4 = *(const float4*)&rt[row][4 * g];
      float lv = rt[row][li];
      float rv = rt[row][ri];
      float v[6] = {lv, c4.x, c4.y, c4.z, c4.w, rv};
#pragma unroll
      for (int j = 0; j < 6; ++j) {
        cs[j] += v[j];
        cq[j] += v[j] * v[j];
      }
    }
    float4 f4 = *(const float4*)&ft[orow][4 * g];
    const float fv[4] = {f4.x, f4.y, f4.z, f4.w};
#pragma unroll
    for (int c = 0; c < 4; ++c) {
      float s = cs[c] + cs[c + 1] + cs[c + 2];
      float q = cq[c] + cq[c + 1] + cq[c + 2];
      float pvar = (q - s * s / 9.0f) / 8.0f;
      v3 += pvar * fv[c];
    }
  }

#pragma unroll
  for (int off = 32; off > 0; off >>= 1) v3 += __shfl_down(v3, off, 64);
  __syncthreads();  // stage-B reads done before LDS reuse
  const int wave = tid >> 6, lane = tid & 63;
  if (lane == 0) rt[0][wave] = v3;
  __syncthreads();
  if (tid == 0) p_loss[bid] = rt[0][0] + rt[0][1] + rt[0][2] + rt[0][3];
}

// ---------------- Pass 3: fold partials ----------------------------------
__global__ __launch_bounds__(1024) void wl1_reduce(
    const float* __restrict__ p_sum, const float* __restrict__ p_sum2,
    const float* __restrict__ p_loss, float* __restrict__ out) {
  const int tid = threadIdx.x;
  const int b = tid >> 6, k = tid & 63;
  double s = 0.0, s2 = 0.0, sl = 0.0;
#pragma unroll
  for (int j = 0; j < P1_PER_B; j += 64) {
    int i = b * P1_PER_B + j + k;
    s += (double)p_sum[i];
    s2 += (double)p_sum2[i];
  }
#pragma unroll
  for (int j = 0; j < P2_PER_B; j += 64) {
    sl += (double)p_loss[b * P2_PER_B + j + k];
  }
#pragma unroll
  for (int off = 32; off > 0; off >>= 1) {
    s += __shfl_down(s, off, 64);
    s2 += __shfl_down(s2, off, 64);
    sl += __shfl_down(sl, off, 64);
  }
  __shared__ double acc[BB];
  if (k == 0) {
    const double n = (double)HW;
    double var = (s2 - s * s / n) / (n - 1.0);
    acc[b] = pow(var, 0.2) * sl;
  }
  __syncthreads();
  if (tid == 0) {
    double tot = 0.0;
#pragma unroll
    for (int j = 0; j < BB; ++j) tot += acc[j];
    out[0] = (float)(tot / (double)((size_t)BB * CHW));
  }
}

extern "C" void kernel_launch(void* const* d_in, const int* in_sizes, int n_in,
                              void* d_out, int out_size, void* d_ws,
                              size_t ws_size, hipStream_t stream) {
  const float* sr = (const float*)d_in[0];
  const float* srema = (const float*)d_in[1];
  const float* hr = (const float*)d_in[2];
  float* out = (float*)d_out;

  // ws layout: rfbuf (16 MiB) | p_sum (4096) | p_sum2 (4096) | p_loss (2048)
  float4* rfbuf = (float4*)d_ws;
  float* p_sum = (float*)((char*)d_ws + (size_t)NGRP * sizeof(float4));
  float* p_sum2 = p_sum + 2 * P1_BLOCKS;
  float* p_loss = p_sum2 + 2 * P1_BLOCKS;

  wl1_pass1<<<P1_BLOCKS, 256, 0, stream>>>(sr, srema, hr, rfbuf, p_sum, p_sum2);
  wl1_pass2<<<P2_BLOCKS, 256, 0, stream>>>(rfbuf, p_loss);
  wl1_reduce<<<1, 1024, 0, stream>>>(p_sum, p_sum2, p_loss, out);
}